// Round 11
// baseline (57.201 us; speedup 1.0000x reference)
//
#include <hip/hip_runtime.h>
#include <math.h>

// Segment mean via 3-kernel decomposition (each kernel single-regime):
//   A compact: dense float4 stream of edge_x -> val[] (col 0), pure BW.
//   B sort:    dense int4/float4 read of dst+val (25.6 MB only), LDS
//              counting sort per 6252-edge chunk, dense pairs writeout,
//              TRANSPOSED boff_t[bucket][chunk] for dense reads in C.
//   C reduce:  per-bucket block; dense boff_t rows -> LDS, gather runs
//              (avg 16 consecutive u32), packed-double LDS accumulate.
// Fallback to packed-f64-atomic scatter if ws is too small.

#define PACK_MAGIC 4294967296.0   // 2^32
#define NB 391                    // ceil(100000 / 256)
#define BSHIFT 8
#define SNODES 256
#define NC 512                    // chunks (= B blocks)
#define CMAXR 6400                // max chunkR staged in LDS (u32)
#define T1B 512                   // B block size
#define T2 512                    // C block size

__device__ __forceinline__ unsigned pack_pair(float v, int local) {
    unsigned b = __float_as_uint(v);
    b = (b + 0x80u) & 0xFFFFFF00u;           // round mantissa to 15 bits
    return b | (unsigned)local;
}

// ---------- A: compact col0 (pure streaming) ----------
__global__ void compact_kernel(const float* __restrict__ edge_x,
                               float* __restrict__ val, int n_edges) {
    const float4* ex4 = reinterpret_cast<const float4*>(edge_x);
    int cap = 2 * n_edges;                    // row r = float4s {2r, 2r+1}
    int g = blockIdx.x * blockDim.x + threadIdx.x;
    int stride = gridDim.x * blockDim.x;
    for (; g < cap; g += stride) {
        float4 v = ex4[g];
        if (!(g & 1)) val[g >> 1] = v.x;      // dense requests, dense writes
    }
}

// ---------- B: LDS counting sort from compact inputs ----------
__global__ void __launch_bounds__(T1B)
sort_kernel(const float* __restrict__ val,
            const int* __restrict__ dst,
            unsigned* __restrict__ pairs,
            int* __restrict__ boff_t,         // [(NB+1)][NC]
            int n_edges, int chunkR) {
    __shared__ unsigned s_data[CMAXR];
    __shared__ int h[NB];
    __shared__ int cnt[NB];

    int tid = threadIdx.x, blk = blockIdx.x;
    long beg = (long)blk * chunkR;
    long rem = (long)n_edges - beg;
    int chunkN = (rem < 0) ? 0 : (int)min((long)chunkR, rem);

    // dense vector loads of this thread's 16 edges (4 groups of int4/float4)
    int4   rd[4];
    float4 rv[4];
#pragma unroll
    for (int k = 0; k < 4; ++k) {
        int g = tid + k * T1B;                // int4 index within chunk
        int r0 = g * 4;
        if (r0 + 3 < chunkN) {
            rd[k] = *reinterpret_cast<const int4*>(dst + beg + r0);
            rv[k] = *reinterpret_cast<const float4*>(val + beg + r0);
        } else {
            rd[k].x = (r0 + 0 < chunkN) ? dst[beg + r0 + 0] : -1;
            rd[k].y = (r0 + 1 < chunkN) ? dst[beg + r0 + 1] : -1;
            rd[k].z = (r0 + 2 < chunkN) ? dst[beg + r0 + 2] : -1;
            rd[k].w = (r0 + 3 < chunkN) ? dst[beg + r0 + 3] : -1;
            rv[k].x = (r0 + 0 < chunkN) ? val[beg + r0 + 0] : 0.0f;
            rv[k].y = (r0 + 1 < chunkN) ? val[beg + r0 + 1] : 0.0f;
            rv[k].z = (r0 + 2 < chunkN) ? val[beg + r0 + 2] : 0.0f;
            rv[k].w = (r0 + 3 < chunkN) ? val[beg + r0 + 3] : 0.0f;
        }
    }

    for (int b = tid; b < NB; b += T1B) h[b] = 0;
    __syncthreads();

    // histogram
#pragma unroll
    for (int k = 0; k < 4; ++k) {
        if (rd[k].x >= 0) atomicAdd(&h[rd[k].x >> BSHIFT], 1);
        if (rd[k].y >= 0) atomicAdd(&h[rd[k].y >> BSHIFT], 1);
        if (rd[k].z >= 0) atomicAdd(&h[rd[k].z >> BSHIFT], 1);
        if (rd[k].w >= 0) atomicAdd(&h[rd[k].w >> BSHIFT], 1);
    }
    __syncthreads();

    // wave 0: exclusive scan h -> cnt; store TRANSPOSED boff column
    if (tid < 64) {
        int lane = tid;
        const int K = (NB + 63) / 64;  // 7
        int vals[7];
        int local = 0;
#pragma unroll
        for (int k = 0; k < K; ++k) {
            int idx = lane * K + k;
            int v = (idx < NB) ? h[idx] : 0;
            vals[k] = v; local += v;
        }
        int s = local;
        for (int off = 1; off < 64; off <<= 1) {
            int t = __shfl_up(s, off);
            if (lane >= off) s += t;
        }
        int ex = s - local;
#pragma unroll
        for (int k = 0; k < K; ++k) {
            int idx = lane * K + k;
            if (idx < NB) { cnt[idx] = ex; boff_t[(size_t)idx * NC + blk] = ex; }
            ex += vals[k];
        }
        if (lane == 63) boff_t[(size_t)NB * NC + blk] = ex;   // total
    }
    __syncthreads();

    // stage into sorted LDS positions (all inputs in registers)
#pragma unroll
    for (int k = 0; k < 4; ++k) {
        int d;
        d = rd[k].x;
        if (d >= 0) { int p = atomicAdd(&cnt[d >> BSHIFT], 1);
                      s_data[p] = pack_pair(rv[k].x, d & (SNODES - 1)); }
        d = rd[k].y;
        if (d >= 0) { int p = atomicAdd(&cnt[d >> BSHIFT], 1);
                      s_data[p] = pack_pair(rv[k].y, d & (SNODES - 1)); }
        d = rd[k].z;
        if (d >= 0) { int p = atomicAdd(&cnt[d >> BSHIFT], 1);
                      s_data[p] = pack_pair(rv[k].z, d & (SNODES - 1)); }
        d = rd[k].w;
        if (d >= 0) { int p = atomicAdd(&cnt[d >> BSHIFT], 1);
                      s_data[p] = pack_pair(rv[k].w, d & (SNODES - 1)); }
    }
    __syncthreads();

    // dense coalesced writeout (uint4)
    unsigned* outp = pairs + (size_t)blk * chunkR;
    for (int p = tid * 4; p < chunkN; p += T1B * 4) {
        if (p + 4 <= chunkN) {
            *reinterpret_cast<uint4*>(outp + p) =
                *reinterpret_cast<const uint4*>(&s_data[p]);
        } else {
            for (int q = p; q < chunkN; ++q) outp[q] = s_data[q];
        }
    }
}

// ---------- C: per-bucket reduce with dense offset rows ----------
__global__ void __launch_bounds__(T2)
reduce_kernel(const unsigned* __restrict__ pairs,
              const int* __restrict__ boff_t,
              float* __restrict__ out, int n_nodes, int chunkR) {
    __shared__ double acc[SNODES];
    __shared__ int s_lo[NC];
    __shared__ int s_hi[NC];
    int b = blockIdx.x, tid = threadIdx.x;

    for (int i = tid; i < SNODES; i += T2) acc[i] = 0.0;
    for (int c = tid; c < NC; c += T2) {       // dense row reads
        s_lo[c] = boff_t[(size_t)b * NC + c];
        s_hi[c] = boff_t[(size_t)(b + 1) * NC + c];
    }
    __syncthreads();

    for (int c = tid; c < NC; c += T2) {
        int lo = s_lo[c], hi = s_hi[c];
        const unsigned* src = pairs + (size_t)c * chunkR;
        for (int j = lo; j < hi; ++j) {
            unsigned p = src[j];
            float v = __uint_as_float(p & 0xFFFFFF00u);
            atomicAdd(&acc[p & 0xFFu], (double)v + PACK_MAGIC);
        }
    }
    __syncthreads();

    int node0 = b << BSHIFT;
    for (int i = tid; i < SNODES; i += T2) {
        int node = node0 + i;
        if (node < n_nodes) {
            double x = acc[i];
            double c2 = nearbyint(x * (1.0 / PACK_MAGIC));
            double s2 = x - c2 * PACK_MAGIC;
            out[node] = (c2 > 0.0) ? (float)(s2 / c2) : 0.0f;
        }
    }
}

// ---------- fallback: packed-f64 atomic path ----------

__global__ void zero_ws_kernel(double* __restrict__ ws, int n) {
    int i = blockIdx.x * blockDim.x + threadIdx.x;
    int stride = gridDim.x * blockDim.x;
    for (; i < n; i += stride) ws[i] = 0.0;
}

__global__ void scatter_atomic_kernel(const float* __restrict__ edge_x,
                                      const int* __restrict__ dst,
                                      double* __restrict__ part,
                                      int n_edges, int n_nodes, int r_mask) {
    int t = blockIdx.x * blockDim.x + threadIdx.x;
    int basei = t * 4;
    double* my = part + (size_t)(blockIdx.x & r_mask) * (size_t)n_nodes;
    if (basei + 3 < n_edges) {
        int4 d4 = *reinterpret_cast<const int4*>(dst + basei);
        float v0 = edge_x[(size_t)(basei + 0) * 8];
        float v1 = edge_x[(size_t)(basei + 1) * 8];
        float v2 = edge_x[(size_t)(basei + 2) * 8];
        float v3 = edge_x[(size_t)(basei + 3) * 8];
        atomicAdd(&my[d4.x], (double)v0 + PACK_MAGIC);
        atomicAdd(&my[d4.y], (double)v1 + PACK_MAGIC);
        atomicAdd(&my[d4.z], (double)v2 + PACK_MAGIC);
        atomicAdd(&my[d4.w], (double)v3 + PACK_MAGIC);
    } else {
        for (int i = basei; i < n_edges; ++i) {
            float v = edge_x[(size_t)i * 8];
            atomicAdd(&my[dst[i]], (double)v + PACK_MAGIC);
        }
    }
}

__global__ void finalize_atomic_kernel(const double* __restrict__ part,
                                       float* __restrict__ out, int n_nodes, int R) {
    int i = blockIdx.x * blockDim.x + threadIdx.x;
    if (i >= n_nodes) return;
    double x = 0.0;
    for (int r = 0; r < R; ++r) x += part[(size_t)r * n_nodes + i];
    double c = nearbyint(x * (1.0 / PACK_MAGIC));
    double s = x - c * PACK_MAGIC;
    out[i] = (c > 0.0) ? (float)(s / c) : 0.0f;
}

// ---------- launch ----------

extern "C" void kernel_launch(void* const* d_in, const int* in_sizes, int n_in,
                              void* d_out, int out_size, void* d_ws, size_t ws_size,
                              hipStream_t stream) {
    const float* edge_x = (const float*)d_in[0];
    const int*   dst    = (const int*)d_in[1];
    float* out = (float*)d_out;

    const int n_nodes = out_size;        // 100000
    const int n_edges = in_sizes[1];     // 3200000

    // chunk rounded to multiple of 4 (vector alignment)
    int chunkR = (((n_edges + NC - 1) / NC) + 3) & ~3;

    size_t val_bytes   = ((size_t)n_edges * sizeof(float) + 255) & ~(size_t)255;
    size_t pairs_bytes = ((size_t)NC * chunkR * sizeof(unsigned) + 255) & ~(size_t)255;
    size_t bofft_bytes = (size_t)(NB + 1) * NC * sizeof(int);
    size_t need = val_bytes + pairs_bytes + bofft_bytes;

    if (ws_size >= need && n_nodes <= NB * SNODES &&
        chunkR <= CMAXR && chunkR <= 16 * T1B) {
        float*    val    = (float*)d_ws;
        unsigned* pairs  = (unsigned*)((char*)d_ws + val_bytes);
        int*      boff_t = (int*)((char*)d_ws + val_bytes + pairs_bytes);

        compact_kernel<<<2048, 256, 0, stream>>>(edge_x, val, n_edges);
        sort_kernel<<<NC, T1B, 0, stream>>>(val, dst, pairs, boff_t,
                                            n_edges, chunkR);
        reduce_kernel<<<NB, T2, 0, stream>>>(pairs, boff_t, out, n_nodes, chunkR);
    } else {
        int R = 1;
        while (R < 8 && (size_t)(R * 2) * (size_t)n_nodes * sizeof(double) <= ws_size) R *= 2;
        double* part = (double*)d_ws;
        {
            int n = R * n_nodes;
            int blocks = min((n + 255) / 256, 2048);
            zero_ws_kernel<<<blocks, 256, 0, stream>>>(part, n);
        }
        {
            int nthreads = (n_edges + 3) / 4;
            int blocks = (nthreads + 255) / 256;
            scatter_atomic_kernel<<<blocks, 256, 0, stream>>>(edge_x, dst, part,
                                                              n_edges, n_nodes, R - 1);
        }
        {
            int blocks = (n_nodes + 255) / 256;
            finalize_atomic_kernel<<<blocks, 256, 0, stream>>>(part, out, n_nodes, R);
        }
    }
}

// Round 12
// 53.065 us; speedup vs baseline: 1.0779x; 1.0779x over previous
//
#include <hip/hip_runtime.h>
#include <math.h>

// Segment mean via block-local counting sort + run-gather reduce.
//   K1 (IDENTICAL to R9 baseline): per-thread register prefetch of
//       dst+edge_x, LDS histogram + scan (boff row from scan regs),
//       LDS counting sort, dense uint4 writeout.
//   K2 (NEW): per-bucket block; 16-lane SUBGROUP per chunk-run (one
//       coalesced 64B load per run, 64 subgroups in flight), accumulate
//       with NATIVE LDS atomics (ds_add_f32 + ds_add_u32, no f64 CAS).
// A/B discipline: only K2 changed vs R9 -> delta total = delta K2.
// Fallback to packed-f64-atomic scatter if ws is too small.

#define PACK_MAGIC 4294967296.0   // 2^32 (fallback path only)
#define NB 391                    // ceil(100000 / 256)
#define BSHIFT 8
#define SNODES 256
#define NC 512                    // chunks (= K1 blocks)
#define CMAXR 6400                // max chunkR staged in LDS (u32)
#define T1 1024                   // K1 block size (16 waves)
#define EPT 7                     // edges per thread: chunkR <= T1*EPT
#define T2 1024                   // K2 block size (64 subgroups of 16)

__device__ __forceinline__ unsigned pack_pair(float v, int local) {
    unsigned b = __float_as_uint(v);
    b = (b + 0x80u) & 0xFFFFFF00u;           // round mantissa to 15 bits
    return b | (unsigned)local;
}

// K1: reg prefetch -> hist -> scan(+boff store) -> LDS sort -> dense writeout
__global__ void __launch_bounds__(T1)
sort_kernel(const float* __restrict__ edge_x,
            const int* __restrict__ dst,
            unsigned* __restrict__ pairs,
            int* __restrict__ boff,
            int n_edges, int chunkR) {
    __shared__ unsigned s_data[CMAXR];
    __shared__ int h[NB];     // chunk bucket counts
    __shared__ int cnt[NB];   // cursors (start at exclusive-scan positions)

    int tid = threadIdx.x, blk = blockIdx.x;
    long beg = (long)blk * chunkR;
    long rem = (long)n_edges - beg;
    int chunkN = (rem < 0) ? 0 : (int)min((long)chunkR, rem);

    // prefetch ALL this thread's edges into registers (deep ILP, one round)
    int   rd[EPT];
    float rv[EPT];
#pragma unroll
    for (int k = 0; k < EPT; ++k) {
        int i = tid + k * T1;
        bool ok = (i < chunkN);
        rd[k] = ok ? dst[beg + i] : -1;
        rv[k] = ok ? edge_x[(size_t)(beg + i) * 8] : 0.0f;
    }

    for (int b = tid; b < NB; b += T1) h[b] = 0;
    __syncthreads();

    // histogram from registers
#pragma unroll
    for (int k = 0; k < EPT; ++k)
        if (rd[k] >= 0) atomicAdd(&h[rd[k] >> BSHIFT], 1);
    __syncthreads();

    // wave 0: exclusive scan h -> cnt, store boff row from registers
    if (tid < 64) {
        int lane = tid;
        const int K = (NB + 63) / 64;  // 7
        int vals[7];
        int local = 0;
#pragma unroll
        for (int k = 0; k < K; ++k) {
            int idx = lane * K + k;
            int v = (idx < NB) ? h[idx] : 0;
            vals[k] = v; local += v;
        }
        int s = local;
        for (int off = 1; off < 64; off <<= 1) {
            int t = __shfl_up(s, off);
            if (lane >= off) s += t;
        }
        int ex = s - local;
        int* row = boff + (size_t)blk * (NB + 1);
#pragma unroll
        for (int k = 0; k < K; ++k) {
            int idx = lane * K + k;
            if (idx < NB) { cnt[idx] = ex; row[idx] = ex; }
            ex += vals[k];
        }
        if (lane == 0) row[NB] = chunkN;
    }
    __syncthreads();

    // stage into sorted LDS positions
#pragma unroll
    for (int k = 0; k < EPT; ++k) {
        if (rd[k] >= 0) {
            int b = rd[k] >> BSHIFT;
            int p = atomicAdd(&cnt[b], 1);
            s_data[p] = pack_pair(rv[k], rd[k] & (SNODES - 1));
        }
    }
    __syncthreads();

    // dense coalesced writeout (uint4)
    unsigned* outp = pairs + (size_t)blk * chunkR;
    for (int p = tid * 4; p < chunkN; p += T1 * 4) {
        if (p + 4 <= chunkN) {
            *reinterpret_cast<uint4*>(outp + p) =
                *reinterpret_cast<const uint4*>(&s_data[p]);
        } else {
            for (int q = p; q < chunkN; ++q) outp[q] = s_data[q];
        }
    }
}

// K2: per-bucket block; 16-lane subgroup per run; native f32/u32 LDS atomics
__global__ void __launch_bounds__(T2)
reduce_kernel(const unsigned* __restrict__ pairs,
              const int* __restrict__ boff,
              float* __restrict__ out, int n_nodes, int chunkR) {
    __shared__ float s_sum[SNODES];
    __shared__ int   s_cnt[SNODES];
    __shared__ int   s_lo[NC];
    __shared__ int   s_hi[NC];

    int b = blockIdx.x, tid = threadIdx.x;
    for (int i = tid; i < SNODES; i += T2) { s_sum[i] = 0.0f; s_cnt[i] = 0; }
    for (int c = tid; c < NC; c += T2) {
        const int* row = boff + (size_t)c * (NB + 1);
        s_lo[c] = row[b];
        s_hi[c] = row[b + 1];
    }
    __syncthreads();

    // 64 subgroups of 16 lanes; subgroup walks chunks, one coalesced
    // 64B-ish load per run, lanes cover run entries in parallel
    int lane16 = tid & 15;
    int sub = tid >> 4;                      // 0..63
    for (int c = sub; c < NC; c += (T2 >> 4)) {
        int lo = s_lo[c], hi = s_hi[c];
        const unsigned* src = pairs + (size_t)c * chunkR;
        for (int j = lo + lane16; j < hi; j += 16) {
            unsigned p = src[j];
            float v = __uint_as_float(p & 0xFFFFFF00u);
            atomicAdd(&s_sum[p & 0xFFu], v);      // native ds_add_f32
            atomicAdd(&s_cnt[p & 0xFFu], 1);      // native ds_add_u32
        }
    }
    __syncthreads();

    int node0 = b << BSHIFT;
    for (int i = tid; i < SNODES; i += T2) {
        int node = node0 + i;
        if (node < n_nodes) {
            int c = s_cnt[i];
            out[node] = (c > 0) ? (s_sum[i] / (float)c) : 0.0f;
        }
    }
}

// ---------- fallback: packed-f64 atomic path ----------

__global__ void zero_ws_kernel(double* __restrict__ ws, int n) {
    int i = blockIdx.x * blockDim.x + threadIdx.x;
    int stride = gridDim.x * blockDim.x;
    for (; i < n; i += stride) ws[i] = 0.0;
}

__global__ void scatter_atomic_kernel(const float* __restrict__ edge_x,
                                      const int* __restrict__ dst,
                                      double* __restrict__ part,
                                      int n_edges, int n_nodes, int r_mask) {
    int t = blockIdx.x * blockDim.x + threadIdx.x;
    int basei = t * 4;
    double* my = part + (size_t)(blockIdx.x & r_mask) * (size_t)n_nodes;
    if (basei + 3 < n_edges) {
        int4 d4 = *reinterpret_cast<const int4*>(dst + basei);
        float v0 = edge_x[(size_t)(basei + 0) * 8];
        float v1 = edge_x[(size_t)(basei + 1) * 8];
        float v2 = edge_x[(size_t)(basei + 2) * 8];
        float v3 = edge_x[(size_t)(basei + 3) * 8];
        atomicAdd(&my[d4.x], (double)v0 + PACK_MAGIC);
        atomicAdd(&my[d4.y], (double)v1 + PACK_MAGIC);
        atomicAdd(&my[d4.z], (double)v2 + PACK_MAGIC);
        atomicAdd(&my[d4.w], (double)v3 + PACK_MAGIC);
    } else {
        for (int i = basei; i < n_edges; ++i) {
            float v = edge_x[(size_t)i * 8];
            atomicAdd(&my[dst[i]], (double)v + PACK_MAGIC);
        }
    }
}

__global__ void finalize_atomic_kernel(const double* __restrict__ part,
                                       float* __restrict__ out, int n_nodes, int R) {
    int i = blockIdx.x * blockDim.x + threadIdx.x;
    if (i >= n_nodes) return;
    double x = 0.0;
    for (int r = 0; r < R; ++r) x += part[(size_t)r * n_nodes + i];
    double c = nearbyint(x * (1.0 / PACK_MAGIC));
    double s = x - c * PACK_MAGIC;
    out[i] = (c > 0.0) ? (float)(s / c) : 0.0f;
}

// ---------- launch ----------

extern "C" void kernel_launch(void* const* d_in, const int* in_sizes, int n_in,
                              void* d_out, int out_size, void* d_ws, size_t ws_size,
                              hipStream_t stream) {
    const float* edge_x = (const float*)d_in[0];
    const int*   dst    = (const int*)d_in[1];
    float* out = (float*)d_out;

    const int n_nodes = out_size;        // 100000
    const int n_edges = in_sizes[1];     // 3200000

    // chunk rounded to multiple of 4 (uint4 writeout alignment)
    int chunkR = (((n_edges + NC - 1) / NC) + 3) & ~3;

    size_t pairs_bytes = (size_t)NC * chunkR * sizeof(unsigned);
    size_t boff_bytes  = (size_t)NC * (NB + 1) * sizeof(int);
    size_t need = pairs_bytes + boff_bytes;

    if (ws_size >= need && n_nodes <= NB * SNODES &&
        chunkR <= CMAXR && chunkR <= T1 * EPT) {
        unsigned* pairs = (unsigned*)d_ws;
        int* boff = (int*)((char*)d_ws + pairs_bytes);

        sort_kernel<<<NC, T1, 0, stream>>>(edge_x, dst, pairs, boff,
                                           n_edges, chunkR);
        reduce_kernel<<<NB, T2, 0, stream>>>(pairs, boff, out, n_nodes, chunkR);
    } else {
        int R = 1;
        while (R < 8 && (size_t)(R * 2) * (size_t)n_nodes * sizeof(double) <= ws_size) R *= 2;
        double* part = (double*)d_ws;
        {
            int n = R * n_nodes;
            int blocks = min((n + 255) / 256, 2048);
            zero_ws_kernel<<<blocks, 256, 0, stream>>>(part, n);
        }
        {
            int nthreads = (n_edges + 3) / 4;
            int blocks = (nthreads + 255) / 256;
            scatter_atomic_kernel<<<blocks, 256, 0, stream>>>(edge_x, dst, part,
                                                              n_edges, n_nodes, R - 1);
        }
        {
            int blocks = (n_nodes + 255) / 256;
            finalize_atomic_kernel<<<blocks, 256, 0, stream>>>(part, out, n_nodes, R);
        }
    }
}

// Round 13
// 36.729 us; speedup vs baseline: 1.5574x; 1.4448x over previous
//
#include <hip/hip_runtime.h>
#include <math.h>

// Segment mean via block-local counting sort + run-gather reduce.
//   BSHIFT=9: 196 buckets x 512 nodes; K2 runs avg 32 entries (128B gathers).
//   K1: per-thread register prefetch of dst+edge_x, LDS histogram + scan
//       (TRANSPOSED boff_t written from scan regs), LDS counting sort,
//       dense uint4 writeout.
//   K2: per-bucket block; 16-lane subgroup per chunk-run; packed-double
//       LDS accumulate (sum + 2^32*count in one atomic).
// Fallback to packed-f64-atomic scatter if ws is too small.

#define PACK_MAGIC 4294967296.0   // 2^32
#define NB 196                    // ceil(100000 / 512)
#define BSHIFT 9
#define SNODES 512
#define NC 512                    // chunks (= K1 blocks)
#define CMAXR 6400                // max chunkR staged in LDS (u32)
#define T1 1024                   // K1 block size (16 waves)
#define EPT 7                     // edges per thread: chunkR <= T1*EPT
#define T2 1024                   // K2 block size (64 subgroups of 16)

__device__ __forceinline__ unsigned pack_pair(float v, int local) {
    unsigned b = __float_as_uint(v);
    b = (b + 0x100u) & 0xFFFFFE00u;          // round mantissa to 14 bits
    return b | (unsigned)local;              // 9-bit intra-bucket index
}

// K1: reg prefetch -> hist -> scan(+boff_t store) -> LDS sort -> dense writeout
__global__ void __launch_bounds__(T1)
sort_kernel(const float* __restrict__ edge_x,
            const int* __restrict__ dst,
            unsigned* __restrict__ pairs,
            int* __restrict__ boff_t,        // [(NB+1)][NC] transposed
            int n_edges, int chunkR) {
    __shared__ unsigned s_data[CMAXR];
    __shared__ int h[NB];     // chunk bucket counts
    __shared__ int cnt[NB];   // cursors (start at exclusive-scan positions)

    int tid = threadIdx.x, blk = blockIdx.x;
    long beg = (long)blk * chunkR;
    long rem = (long)n_edges - beg;
    int chunkN = (rem < 0) ? 0 : (int)min((long)chunkR, rem);

    // prefetch ALL this thread's edges into registers (deep ILP, one round)
    int   rd[EPT];
    float rv[EPT];
#pragma unroll
    for (int k = 0; k < EPT; ++k) {
        int i = tid + k * T1;
        bool ok = (i < chunkN);
        rd[k] = ok ? dst[beg + i] : -1;
        rv[k] = ok ? edge_x[(size_t)(beg + i) * 8] : 0.0f;
    }

    for (int b = tid; b < NB; b += T1) h[b] = 0;
    __syncthreads();

    // histogram from registers
#pragma unroll
    for (int k = 0; k < EPT; ++k)
        if (rd[k] >= 0) atomicAdd(&h[rd[k] >> BSHIFT], 1);
    __syncthreads();

    // wave 0: exclusive scan h -> cnt, store transposed boff_t column
    if (tid < 64) {
        int lane = tid;
        const int K = (NB + 63) / 64;  // 4
        int vals[4];
        int local = 0;
#pragma unroll
        for (int k = 0; k < K; ++k) {
            int idx = lane * K + k;
            int v = (idx < NB) ? h[idx] : 0;
            vals[k] = v; local += v;
        }
        int s = local;
        for (int off = 1; off < 64; off <<= 1) {
            int t = __shfl_up(s, off);
            if (lane >= off) s += t;
        }
        int ex = s - local;
#pragma unroll
        for (int k = 0; k < K; ++k) {
            int idx = lane * K + k;
            if (idx < NB) { cnt[idx] = ex; boff_t[(size_t)idx * NC + blk] = ex; }
            ex += vals[k];
        }
        if (lane == 63) boff_t[(size_t)NB * NC + blk] = ex;   // total
    }
    __syncthreads();

    // stage into sorted LDS positions
#pragma unroll
    for (int k = 0; k < EPT; ++k) {
        if (rd[k] >= 0) {
            int b = rd[k] >> BSHIFT;
            int p = atomicAdd(&cnt[b], 1);
            s_data[p] = pack_pair(rv[k], rd[k] & (SNODES - 1));
        }
    }
    __syncthreads();

    // dense coalesced writeout (uint4)
    unsigned* outp = pairs + (size_t)blk * chunkR;
    for (int p = tid * 4; p < chunkN; p += T1 * 4) {
        if (p + 4 <= chunkN) {
            *reinterpret_cast<uint4*>(outp + p) =
                *reinterpret_cast<const uint4*>(&s_data[p]);
        } else {
            for (int q = p; q < chunkN; ++q) outp[q] = s_data[q];
        }
    }
}

// K2: per-bucket block; 16-lane subgroup per run; packed-double LDS accumulate
__global__ void __launch_bounds__(T2)
reduce_kernel(const unsigned* __restrict__ pairs,
              const int* __restrict__ boff_t,
              float* __restrict__ out, int n_nodes, int chunkR) {
    __shared__ double acc[SNODES];
    __shared__ int s_lo[NC];
    __shared__ int s_hi[NC];

    int b = blockIdx.x, tid = threadIdx.x;
    for (int i = tid; i < SNODES; i += T2) acc[i] = 0.0;
    for (int c = tid; c < NC; c += T2) {          // dense transposed rows
        s_lo[c] = boff_t[(size_t)b * NC + c];
        s_hi[c] = boff_t[(size_t)(b + 1) * NC + c];
    }
    __syncthreads();

    int lane16 = tid & 15;
    int sub = tid >> 4;                           // 0..63
    for (int c = sub; c < NC; c += (T2 >> 4)) {
        int lo = s_lo[c], hi = s_hi[c];
        const unsigned* src = pairs + (size_t)c * chunkR;
        for (int j = lo + lane16; j < hi; j += 16) {
            unsigned p = src[j];
            float v = __uint_as_float(p & 0xFFFFFE00u);
            atomicAdd(&acc[p & 0x1FFu], (double)v + PACK_MAGIC);
        }
    }
    __syncthreads();

    int node0 = b << BSHIFT;
    for (int i = tid; i < SNODES; i += T2) {
        int node = node0 + i;
        if (node < n_nodes) {
            double x = acc[i];
            double c2 = nearbyint(x * (1.0 / PACK_MAGIC));
            double s2 = x - c2 * PACK_MAGIC;
            out[node] = (c2 > 0.0) ? (float)(s2 / c2) : 0.0f;
        }
    }
}

// ---------- fallback: packed-f64 atomic path ----------

__global__ void zero_ws_kernel(double* __restrict__ ws, int n) {
    int i = blockIdx.x * blockDim.x + threadIdx.x;
    int stride = gridDim.x * blockDim.x;
    for (; i < n; i += stride) ws[i] = 0.0;
}

__global__ void scatter_atomic_kernel(const float* __restrict__ edge_x,
                                      const int* __restrict__ dst,
                                      double* __restrict__ part,
                                      int n_edges, int n_nodes, int r_mask) {
    int t = blockIdx.x * blockDim.x + threadIdx.x;
    int basei = t * 4;
    double* my = part + (size_t)(blockIdx.x & r_mask) * (size_t)n_nodes;
    if (basei + 3 < n_edges) {
        int4 d4 = *reinterpret_cast<const int4*>(dst + basei);
        float v0 = edge_x[(size_t)(basei + 0) * 8];
        float v1 = edge_x[(size_t)(basei + 1) * 8];
        float v2 = edge_x[(size_t)(basei + 2) * 8];
        float v3 = edge_x[(size_t)(basei + 3) * 8];
        atomicAdd(&my[d4.x], (double)v0 + PACK_MAGIC);
        atomicAdd(&my[d4.y], (double)v1 + PACK_MAGIC);
        atomicAdd(&my[d4.z], (double)v2 + PACK_MAGIC);
        atomicAdd(&my[d4.w], (double)v3 + PACK_MAGIC);
    } else {
        for (int i = basei; i < n_edges; ++i) {
            float v = edge_x[(size_t)i * 8];
            atomicAdd(&my[dst[i]], (double)v + PACK_MAGIC);
        }
    }
}

__global__ void finalize_atomic_kernel(const double* __restrict__ part,
                                       float* __restrict__ out, int n_nodes, int R) {
    int i = blockIdx.x * blockDim.x + threadIdx.x;
    if (i >= n_nodes) return;
    double x = 0.0;
    for (int r = 0; r < R; ++r) x += part[(size_t)r * n_nodes + i];
    double c = nearbyint(x * (1.0 / PACK_MAGIC));
    double s = x - c * PACK_MAGIC;
    out[i] = (c > 0.0) ? (float)(s / c) : 0.0f;
}

// ---------- launch ----------

extern "C" void kernel_launch(void* const* d_in, const int* in_sizes, int n_in,
                              void* d_out, int out_size, void* d_ws, size_t ws_size,
                              hipStream_t stream) {
    const float* edge_x = (const float*)d_in[0];
    const int*   dst    = (const int*)d_in[1];
    float* out = (float*)d_out;

    const int n_nodes = out_size;        // 100000
    const int n_edges = in_sizes[1];     // 3200000

    // chunk rounded to multiple of 4 (uint4 writeout alignment)
    int chunkR = (((n_edges + NC - 1) / NC) + 3) & ~3;

    size_t pairs_bytes = (size_t)NC * chunkR * sizeof(unsigned);
    size_t bofft_bytes = (size_t)(NB + 1) * NC * sizeof(int);
    size_t need = pairs_bytes + bofft_bytes;

    if (ws_size >= need && n_nodes <= NB * SNODES &&
        chunkR <= CMAXR && chunkR <= T1 * EPT) {
        unsigned* pairs  = (unsigned*)d_ws;
        int*      boff_t = (int*)((char*)d_ws + pairs_bytes);

        sort_kernel<<<NC, T1, 0, stream>>>(edge_x, dst, pairs, boff_t,
                                           n_edges, chunkR);
        reduce_kernel<<<NB, T2, 0, stream>>>(pairs, boff_t, out, n_nodes, chunkR);
    } else {
        int R = 1;
        while (R < 8 && (size_t)(R * 2) * (size_t)n_nodes * sizeof(double) <= ws_size) R *= 2;
        double* part = (double*)d_ws;
        {
            int n = R * n_nodes;
            int blocks = min((n + 255) / 256, 2048);
            zero_ws_kernel<<<blocks, 256, 0, stream>>>(part, n);
        }
        {
            int nthreads = (n_edges + 3) / 4;
            int blocks = (nthreads + 255) / 256;
            scatter_atomic_kernel<<<blocks, 256, 0, stream>>>(edge_x, dst, part,
                                                              n_edges, n_nodes, R - 1);
        }
        {
            int blocks = (n_nodes + 255) / 256;
            finalize_atomic_kernel<<<blocks, 256, 0, stream>>>(part, out, n_nodes, R);
        }
    }
}